// Round 6
// baseline (214.751 us; speedup 1.0000x reference)
//
#include <hip/hip_runtime.h>
#include <math.h>

#define NE 8
#define KDIM 4096
#define PDIM 64
#define WROWS (KDIM + PDIM)   // 4160
#define EPS_F32 1.1920929e-07f
#define NG 8                  // 8 granules x 2KB per token-row
#define TPW 2                 // tokens per wave
#define WAVES 16              // waves per block (1024 threads)
#define ROWF4 (WROWS / 4)     // 1040 f4 per expert row in LDS
#define LDSF (NE * WROWS)     // 33280 floats = 133120 B

typedef float f4 __attribute__((ext_vector_type(4)));

// Single fused kernel (transpose_w eliminated):
//  - W[4160][8] is staged DIRECTLY into LDS transposed (wlds[e][k]) by each
//    block: 2 f4 loads + 8 scalar ds_writes per k, both sides conflict-free
//    (lanes walk consecutive k). Kills the separate launch + Wt round-trip.
//  - x(0)/x(1) prologue loads are issued BEFORE staging: their HBM latency
//    hides under the W->LDS copy (staging's vmcnt drain completes them).
//  - K-loop now walks 8 granules of 2 KB per token-row (was 16 x 1 KB):
//    each DRAM page visit is a 2 KB burst -> half the page open/close rate
//    of the 1 KB pattern. Chip-wide we run 8192 concurrent row-streams,
//    which oversubscribes the HBM bank pool; burst size per visit is the
//    page-hit lever available without restructuring token ownership.
//  - w reads per j-slice: 8 conflict-free ds_read_b128 (lgkm queue), so the
//    per-granule vm wait is on x only (vmcnt(8): g+1, g+2 in flight).
// Registers: xb 3*2*2 f4 = 48, wb 8 f4 = 32, acc 16, misc ~15 => ~111,
// under the 128 cap from __launch_bounds__(1024, 4). 1 block/CU (133 KB
// LDS), 16 waves = 4/SIMD.
__global__ __launch_bounds__(1024, 4)
void topk_gate(const float* __restrict__ x,
               const float* __restrict__ prompt,
               const float* __restrict__ W,
               const float* __restrict__ b,
               float* __restrict__ out,
               int tokens)
{
    __shared__ float wlds[LDSF];        // 133120 B

    const int tid  = threadIdx.x;
    const int lane = tid & 63;          // 0..63
    const int wid  = tid >> 6;          // 0..15

    const int tbase = (blockIdx.x * WAVES + wid) * TPW;
    const int phase = (blockIdx.x * 5) & 7;

    const f4* xr0 = (const f4*)(x + (size_t)tbase * KDIM);
    const f4* xr1 = (const f4*)(x + (size_t)(tbase + 1) * KDIM);

    f4 xb[3][TPW][2];   // [buffer][row][j] : depth-2 prefetch of 2KB granules

    auto gidx = [&](int g, int j) {
        return ((g + phase) & 7) * 128 + j * 64 + lane;   // f4 units
    };

    // ---- x prologue FIRST: g=0,1 in flight while we stage W ----
    {
        xb[0][0][0] = __builtin_nontemporal_load(xr0 + gidx(0, 0));
        xb[0][0][1] = __builtin_nontemporal_load(xr0 + gidx(0, 1));
        xb[0][1][0] = __builtin_nontemporal_load(xr1 + gidx(0, 0));
        xb[0][1][1] = __builtin_nontemporal_load(xr1 + gidx(0, 1));
        xb[1][0][0] = __builtin_nontemporal_load(xr0 + gidx(1, 0));
        xb[1][0][1] = __builtin_nontemporal_load(xr0 + gidx(1, 1));
        xb[1][1][0] = __builtin_nontemporal_load(xr1 + gidx(1, 0));
        xb[1][1][1] = __builtin_nontemporal_load(xr1 + gidx(1, 1));
    }

    // ---- stage W -> LDS transposed: wlds[e*WROWS + k] = W[k][e] ----
    {
        const f4* w4 = (const f4*)W;    // W row k = w4[2k], w4[2k+1]
#pragma unroll
        for (int it = 0; it < 4; ++it) {
            const int k = tid + it * 1024;          // 0..4095, always valid
            const f4 a = w4[(size_t)k * 2];
            const f4 c = w4[(size_t)k * 2 + 1];
            wlds[0 * WROWS + k] = a.x;
            wlds[1 * WROWS + k] = a.y;
            wlds[2 * WROWS + k] = a.z;
            wlds[3 * WROWS + k] = a.w;
            wlds[4 * WROWS + k] = c.x;
            wlds[5 * WROWS + k] = c.y;
            wlds[6 * WROWS + k] = c.z;
            wlds[7 * WROWS + k] = c.w;
        }
        if (tid < WROWS - 4096) {                   // tail k = 4096..4159
            const int k = tid + 4096;
            const f4 a = w4[(size_t)k * 2];
            const f4 c = w4[(size_t)k * 2 + 1];
            wlds[0 * WROWS + k] = a.x;
            wlds[1 * WROWS + k] = a.y;
            wlds[2 * WROWS + k] = a.z;
            wlds[3 * WROWS + k] = a.w;
            wlds[4 * WROWS + k] = c.x;
            wlds[5 * WROWS + k] = c.y;
            wlds[6 * WROWS + k] = c.z;
            wlds[7 * WROWS + k] = c.w;
        }
    }
    __syncthreads();

    float acc[TPW][NE];
#pragma unroll
    for (int t = 0; t < TPW; ++t)
#pragma unroll
        for (int e = 0; e < NE; ++e) acc[t][e] = 0.f;

    const f4* wlds4 = (const f4*)wlds;

#pragma unroll
    for (int g = 0; g < NG; ++g) {
        // prefetch granule g+2 (4 loads, 2KB contiguous per row)
        if (g + 2 < NG) {
            const int bu = (g + 2) % 3;
            xb[bu][0][0] = __builtin_nontemporal_load(xr0 + gidx(g + 2, 0));
            xb[bu][0][1] = __builtin_nontemporal_load(xr0 + gidx(g + 2, 1));
            xb[bu][1][0] = __builtin_nontemporal_load(xr1 + gidx(g + 2, 0));
            xb[bu][1][1] = __builtin_nontemporal_load(xr1 + gidx(g + 2, 1));
        }

        const int s = g % 3;
#pragma unroll
        for (int j = 0; j < 2; ++j) {
            const int kw = gidx(g, j);
            f4 wb[NE];
#pragma unroll
            for (int e = 0; e < NE; ++e)
                wb[e] = wlds4[e * ROWF4 + kw];
#pragma unroll
            for (int t = 0; t < TPW; ++t) {
                const f4 xv = xb[s][t][j];
#pragma unroll
                for (int e = 0; e < NE; ++e) {
                    acc[t][e] = fmaf(xv.x, wb[e].x, acc[t][e]);
                    acc[t][e] = fmaf(xv.y, wb[e].y, acc[t][e]);
                    acc[t][e] = fmaf(xv.z, wb[e].z, acc[t][e]);
                    acc[t][e] = fmaf(xv.w, wb[e].w, acc[t][e]);
                }
            }
        }
    }

    // prompt part (64 dims): lanes 0..15, w from LDS f4 cols 1024..1039
    if (lane < 16) {
        f4 pv[TPW];
#pragma unroll
        for (int t = 0; t < TPW; ++t)
            pv[t] = *((const f4*)(prompt + (size_t)(tbase + t) * PDIM) + lane);
#pragma unroll
        for (int e = 0; e < NE; ++e) {
            const f4 wv = wlds4[e * ROWF4 + (KDIM / 4) + lane];
#pragma unroll
            for (int t = 0; t < TPW; ++t) {
                acc[t][e] = fmaf(pv[t].x, wv.x, acc[t][e]);
                acc[t][e] = fmaf(pv[t].y, wv.y, acc[t][e]);
                acc[t][e] = fmaf(pv[t].z, wv.z, acc[t][e]);
                acc[t][e] = fmaf(pv[t].w, wv.w, acc[t][e]);
            }
        }
    }

    // butterfly reduce: every lane ends with full logits for both tokens
#pragma unroll
    for (int t = 0; t < TPW; ++t)
#pragma unroll
        for (int e = 0; e < NE; ++e) {
            float v = acc[t][e];
#pragma unroll
            for (int off = 32; off >= 1; off >>= 1)
                v += __shfl_xor(v, off, 64);
            acc[t][e] = v;
        }

    // ---- epilogue: lanes 0..31, lane = tt*16 + kk*8 + ee ----
    const int tt = (lane >> 4) & 1;
    const int kk = (lane >> 3) & 1;
    const int ee = lane & 7;

    float lg[NE];
#pragma unroll
    for (int e = 0; e < NE; ++e) {
        const float v = (tt == 0) ? acc[0][e] : acc[1][e];
        lg[e] = v + b[e];
    }

    // top-2, strict > so smallest index wins ties (jax.lax.top_k semantics)
    float v0 = lg[0]; int i0 = 0;
#pragma unroll
    for (int e = 1; e < NE; ++e)
        if (lg[e] > v0) { v0 = lg[e]; i0 = e; }
    float v1 = (i0 == 0) ? lg[1] : lg[0];
    int   i1 = (i0 == 0) ? 1 : 0;
#pragma unroll
    for (int e = 0; e < NE; ++e)
        if (e != i0 && lg[e] > v1) { v1 = lg[e]; i1 = e; }

    float s = 0.f;
#pragma unroll
    for (int e = 0; e < NE; ++e) s += __expf(lg[e] - v0);
    const float g0 = 1.0f / s;
    const float g1 = __expf(v1 - v0) / s;
    const float denom = fmaxf(g0 + g1, EPS_F32);

    if (lane < 32) {
        const int sel = kk ? i1 : i0;
        const int t_global = tbase + tt;
        out[(size_t)t_global * 16 + kk * 8 + ee] = (ee == sel) ? 1.0f : 0.0f;

        if ((lane & 15) < 2) {
            const float g = (ee == 0) ? (g0 / denom) : (g1 / denom);
            out[(size_t)tokens * 16 + (size_t)t_global * 2 + ee] = g;
        }
    }
}

extern "C" void kernel_launch(void* const* d_in, const int* in_sizes, int n_in,
                              void* d_out, int out_size, void* d_ws, size_t ws_size,
                              hipStream_t stream) {
    const float* x      = (const float*)d_in[0];
    const float* prompt = (const float*)d_in[1];
    const float* W      = (const float*)d_in[2];
    const float* b      = (const float*)d_in[3];
    float* out          = (float*)d_out;
    (void)d_ws; (void)ws_size;

    const int tokens = in_sizes[0] / KDIM;       // 8192

    hipLaunchKernelGGL(topk_gate, dim3(tokens / (WAVES * TPW)), dim3(WAVES * 64),
                       0, stream, x, prompt, W, b, out, tokens);
}

// Round 7
// 206.393 us; speedup vs baseline: 1.0405x; 1.0405x over previous
//
#include <hip/hip_runtime.h>
#include <math.h>

#define NE 8
#define KDIM 4096
#define PDIM 64
#define WROWS (KDIM + PDIM)   // 4160
#define EPS_F32 1.1920929e-07f
#define NCHUNK 16             // 4096 / (64 lanes * 4 floats)
#define DEPTH 4               // prefetch depth-4 => 5 register buffer sets
#define NBUF 5
#define TPW 2                 // tokens per wave
#define WAVES 16              // waves per block (1024 threads)
#define ROWF4 (WROWS / 4)     // 1040 f4 per expert row in LDS
#define LDSF (NE * WROWS)     // 33280 floats = 133120 B

typedef float f4 __attribute__((ext_vector_type(4)));

// R5 structure (best: 202.4) + fusion + depth-4 prefetch. R6's NG=8 granule
// restructure REVERTED (it regressed: 48-reg xb + coarser 8-way stagger +
// 4-load drains). Changes vs R5:
//  - transpose_w launch eliminated: W[4160][8] staged directly into LDS
//    transposed (scalar ds_writes, conflict-free; same 133 KB/block read
//    volume as R5's Wt copy, so cost is launch-removal only).
//  - x chunks 0..3 issued BEFORE staging: their HBM latency hides under the
//    W->LDS copy (staging's vmcnt drain completes them for free).
//  - x prefetch depth 2 -> 4 (5 buffers): per-wave in-flight x doubles to
//    ~10 KB, pre-FMA wait is vmcnt(8). Cross-round pipe arithmetic says the
//    kernel is latency-bound (VALU 3.4us, LDS 10us, per-CU HBM 8.7 of 24
//    GB/s all unsaturated at ~60us) -> depth is the matching lever.
// Registers: xb 5*2 f4 = 40, wb 8 f4 = 32 (transient), acc 16, misc ~20
// => ~110 < 128 cap from __launch_bounds__(1024, 4). 16 waves = 4/SIMD,
// 1 block/CU (133 KB LDS), grid 256.
__global__ __launch_bounds__(1024, 4)
void topk_gate(const float* __restrict__ x,
               const float* __restrict__ prompt,
               const float* __restrict__ W,
               const float* __restrict__ b,
               float* __restrict__ out,
               int tokens)
{
    __shared__ float wlds[LDSF];        // 133120 B

    const int tid  = threadIdx.x;
    const int lane = tid & 63;          // 0..63
    const int wid  = tid >> 6;          // 0..15

    const int tbase = (blockIdx.x * WAVES + wid) * TPW;
    const int phase = (blockIdx.x * 5) & 15;

    const f4* xr0 = (const f4*)(x + (size_t)tbase * KDIM);
    const f4* xr1 = (const f4*)(x + (size_t)(tbase + 1) * KDIM);

    f4 xb[NBUF][TPW];   // depth-4 prefetch of 1KB chunks

    auto cidx = [&](int c) { return ((c + phase) & 15) * 64 + lane; };  // f4 units

    // ---- x prologue FIRST: chunks 0..3 in flight while we stage W ----
#pragma unroll
    for (int c = 0; c < DEPTH; ++c) {
        const int k = cidx(c);
        xb[c][0] = __builtin_nontemporal_load(xr0 + k);
        xb[c][1] = __builtin_nontemporal_load(xr1 + k);
    }

    // ---- stage W -> LDS transposed: wlds[e*WROWS + k] = W[k][e] ----
    {
        const f4* w4 = (const f4*)W;    // W row k = w4[2k], w4[2k+1]
#pragma unroll
        for (int it = 0; it < 4; ++it) {
            const int k = tid + it * 1024;          // 0..4095, always valid
            const f4 a = w4[(size_t)k * 2];
            const f4 c = w4[(size_t)k * 2 + 1];
            wlds[0 * WROWS + k] = a.x;
            wlds[1 * WROWS + k] = a.y;
            wlds[2 * WROWS + k] = a.z;
            wlds[3 * WROWS + k] = a.w;
            wlds[4 * WROWS + k] = c.x;
            wlds[5 * WROWS + k] = c.y;
            wlds[6 * WROWS + k] = c.z;
            wlds[7 * WROWS + k] = c.w;
        }
        if (tid < WROWS - 4096) {                   // tail k = 4096..4159
            const int k = tid + 4096;
            const f4 a = w4[(size_t)k * 2];
            const f4 c = w4[(size_t)k * 2 + 1];
            wlds[0 * WROWS + k] = a.x;
            wlds[1 * WROWS + k] = a.y;
            wlds[2 * WROWS + k] = a.z;
            wlds[3 * WROWS + k] = a.w;
            wlds[4 * WROWS + k] = c.x;
            wlds[5 * WROWS + k] = c.y;
            wlds[6 * WROWS + k] = c.z;
            wlds[7 * WROWS + k] = c.w;
        }
    }
    __syncthreads();

    float acc[TPW][NE];
#pragma unroll
    for (int t = 0; t < TPW; ++t)
#pragma unroll
        for (int e = 0; e < NE; ++e) acc[t][e] = 0.f;

    const f4* wlds4 = (const f4*)wlds;

#pragma unroll
    for (int c = 0; c < NCHUNK; ++c) {
        // prefetch chunk c+DEPTH (the only vm-queue traffic in the loop:
        // the FMA's wait on x(c) is vmcnt(8) with 4 chunk-pairs in flight)
        if (c + DEPTH < NCHUNK) {
            const int kx = cidx(c + DEPTH);
            xb[(c + DEPTH) % NBUF][0] = __builtin_nontemporal_load(xr0 + kx);
            xb[(c + DEPTH) % NBUF][1] = __builtin_nontemporal_load(xr1 + kx);
        }

        // w for the CURRENT chunk from LDS (8x conflict-free ds_read_b128)
        const int kw = cidx(c);
        f4 wb[NE];
#pragma unroll
        for (int e = 0; e < NE; ++e)
            wb[e] = wlds4[e * ROWF4 + kw];

        const int s = c % NBUF;
#pragma unroll
        for (int t = 0; t < TPW; ++t)
#pragma unroll
            for (int e = 0; e < NE; ++e) {
                const f4 xv = xb[s][t];
                acc[t][e] = fmaf(xv.x, wb[e].x, acc[t][e]);
                acc[t][e] = fmaf(xv.y, wb[e].y, acc[t][e]);
                acc[t][e] = fmaf(xv.z, wb[e].z, acc[t][e]);
                acc[t][e] = fmaf(xv.w, wb[e].w, acc[t][e]);
            }
    }

    // prompt part (64 dims): lanes 0..15, w from LDS f4 cols 1024..1039
    if (lane < 16) {
        f4 pv[TPW];
#pragma unroll
        for (int t = 0; t < TPW; ++t)
            pv[t] = *((const f4*)(prompt + (size_t)(tbase + t) * PDIM) + lane);
#pragma unroll
        for (int e = 0; e < NE; ++e) {
            const f4 wv = wlds4[e * ROWF4 + (KDIM / 4) + lane];
#pragma unroll
            for (int t = 0; t < TPW; ++t) {
                acc[t][e] = fmaf(pv[t].x, wv.x, acc[t][e]);
                acc[t][e] = fmaf(pv[t].y, wv.y, acc[t][e]);
                acc[t][e] = fmaf(pv[t].z, wv.z, acc[t][e]);
                acc[t][e] = fmaf(pv[t].w, wv.w, acc[t][e]);
            }
        }
    }

    // butterfly reduce: every lane ends with full logits for both tokens
#pragma unroll
    for (int t = 0; t < TPW; ++t)
#pragma unroll
        for (int e = 0; e < NE; ++e) {
            float v = acc[t][e];
#pragma unroll
            for (int off = 32; off >= 1; off >>= 1)
                v += __shfl_xor(v, off, 64);
            acc[t][e] = v;
        }

    // ---- epilogue: lanes 0..31, lane = tt*16 + kk*8 + ee ----
    const int tt = (lane >> 4) & 1;
    const int kk = (lane >> 3) & 1;
    const int ee = lane & 7;

    float lg[NE];
#pragma unroll
    for (int e = 0; e < NE; ++e) {
        const float v = (tt == 0) ? acc[0][e] : acc[1][e];
        lg[e] = v + b[e];
    }

    // top-2, strict > so smallest index wins ties (jax.lax.top_k semantics)
    float v0 = lg[0]; int i0 = 0;
#pragma unroll
    for (int e = 1; e < NE; ++e)
        if (lg[e] > v0) { v0 = lg[e]; i0 = e; }
    float v1 = (i0 == 0) ? lg[1] : lg[0];
    int   i1 = (i0 == 0) ? 1 : 0;
#pragma unroll
    for (int e = 0; e < NE; ++e)
        if (e != i0 && lg[e] > v1) { v1 = lg[e]; i1 = e; }

    float s = 0.f;
#pragma unroll
    for (int e = 0; e < NE; ++e) s += __expf(lg[e] - v0);
    const float g0 = 1.0f / s;
    const float g1 = __expf(v1 - v0) / s;
    const float denom = fmaxf(g0 + g1, EPS_F32);

    if (lane < 32) {
        const int sel = kk ? i1 : i0;
        const int t_global = tbase + tt;
        out[(size_t)t_global * 16 + kk * 8 + ee] = (ee == sel) ? 1.0f : 0.0f;

        if ((lane & 15) < 2) {
            const float g = (ee == 0) ? (g0 / denom) : (g1 / denom);
            out[(size_t)tokens * 16 + (size_t)t_global * 2 + ee] = g;
        }
    }
}

extern "C" void kernel_launch(void* const* d_in, const int* in_sizes, int n_in,
                              void* d_out, int out_size, void* d_ws, size_t ws_size,
                              hipStream_t stream) {
    const float* x      = (const float*)d_in[0];
    const float* prompt = (const float*)d_in[1];
    const float* W      = (const float*)d_in[2];
    const float* b      = (const float*)d_in[3];
    float* out          = (float*)d_out;
    (void)d_ws; (void)ws_size;

    const int tokens = in_sizes[0] / KDIM;       // 8192

    hipLaunchKernelGGL(topk_gate, dim3(tokens / (WAVES * TPW)), dim3(WAVES * 64),
                       0, stream, x, prompt, W, b, out, tokens);
}